// Round 16
// baseline (26113.855 us; speedup 1.0000x reference)
//
#include <hip/hip_runtime.h>
#include <math.h>

#define BB 128   // batch
#define TT 256   // time
#define DD 256   // input dims
#define UU 512   // units
#define RR 512   // ladder order

// ws layout (floats); x_j in XB[j&1], m_j in MB[j&1]:
//   X0  [128][512] @ 0
//   X1  [128][512] @ 65536
//   M0  [128][256] @ 131072
//   M1  [128][256] @ 163840
//   HZ  [128][512] @ 196608   zeros (h_{-1})
//   CNT u32[16]    @ 262144   per-rg x-completion counters (monotonic per call)
#define OFF_X0 0
#define OFF_X1 65536
#define OFF_M0 131072
#define OFF_M1 163840
#define OFF_HZ 196608
#define OFF_CN 262144
#define WS_FLT 262160
#define WS_NEED_BYTES (WS_FLT * 4)

__global__ __launch_bounds__(256) void zero_kernel(float* __restrict__ p, int n)
{
    int i = blockIdx.x * 256 + threadIdx.x;
    if (i < n) p[i] = 0.0f;
}

// combo(t), t = -1..255. Grid 320 x 256:
//   bid   0..127 (h): r8-proven h_t code                                  (t>=0)
//   bid 128..255 (x): r8-proven x_{t+1} code + release-signal cnt[rg]     (t<=254)
//   bid 256..319 (m): wait cnt[rg]==8*(t+2) for its rows' 8 x-tiles, then
//                     m_{t+1} = x_{t+1} @ CT (2 rows/block group of 64)   (t<=254)
// Bitwise contract (= np ref, proven r7/r8): every dot = ascending-k
// single-accumulator fmaf chain from 0.0f; u = inp+m (one add); f = wfm*m
// (one mul); x = aA+aB (one add); z = ((aH+aX)+aF)+by. The m chain here is
// bit-identical to r8's m_kernel (same indexing, same order).
__global__ __launch_bounds__(256) void combo_kernel(
    const float* __restrict__ inputs, const float* __restrict__ wfm,
    const float* __restrict__ by,     const float* __restrict__ WyhT,
    const float* __restrict__ WyxT,   const float* __restrict__ WyfT,
    const float* __restrict__ AT,     const float* __restrict__ BT,
    const float* __restrict__ CT,
    const float* __restrict__ xin,    // x_t
    const float* __restrict__ mc,     // m_t
    const float* __restrict__ hz,     // zeros (h_{-1})
    float* __restrict__ xn,           // x_{t+1}
    float* __restrict__ mn,           // m_{t+1}
    unsigned int* __restrict__ cnt,   // [16]
    float* __restrict__ out, int t)
{
    const int bid  = blockIdx.x;
    const int tid  = threadIdx.x;
    const int lane = tid & 63;
    const int wv   = tid >> 6;

    if (bid < 128) {
        // ================= h-part (r8 code) =================
        if (t < 0) return;
        const int cg_ = bid & 7;
        const int rg  = bid >> 3;
        const int c   = cg_ * 64 + lane;
        const int r0  = rg * 8 + wv * 2;
        const float* h0 = (t == 0) ? (hz + r0 * UU) : (out + (r0 * TT + (t - 1)) * UU);
        const float* h1 = (t == 0) ? (h0 + UU)      : (h0 + TT * UU);
        const float* x0 = xin + r0 * RR;
        const float* x1 = x0 + RR;
        float accH0 = 0.0f, accH1 = 0.0f, accX0 = 0.0f, accX1 = 0.0f;
        #pragma unroll 8
        for (int k = 0; k < UU; ++k) {
            float wh = WyhT[k * UU + c];
            float wx = WyxT[k * UU + c];
            accH0 = fmaf(h0[k], wh, accH0);
            accH1 = fmaf(h1[k], wh, accH1);
            accX0 = fmaf(x0[k], wx, accX0);
            accX1 = fmaf(x1[k], wx, accX1);
        }
        const float* m0 = mc + r0 * DD;
        const float* m1 = m0 + DD;
        float accF0 = 0.0f, accF1 = 0.0f;
        #pragma unroll 16
        for (int d = 0; d < DD; ++d) {
            float w  = WyfT[d * UU + c];
            float f0 = wfm[d] * m0[d];
            float f1 = wfm[d] * m1[d];
            accF0 = fmaf(f0, w, accF0);
            accF1 = fmaf(f1, w, accF1);
        }
        float z0 = ((accH0 + accX0) + accF0) + by[c];
        float z1 = ((accH1 + accX1) + accF1) + by[c];
        out[(r0 * TT + t) * UU + c]       = tanhf(z0);
        out[((r0 + 1) * TT + t) * UU + c] = tanhf(z1);
    } else if (bid < 256) {
        // ================= x-part (r8 code + signal) =================
        if (t >= TT - 1) return;
        const int b   = bid - 128;
        const int cg_ = b & 7;
        const int rg  = b >> 3;
        const int c   = cg_ * 64 + lane;
        const int r0  = rg * 8 + wv * 2;
        const float* x0 = xin + r0 * RR;
        const float* x1 = x0 + RR;
        float a0 = 0.0f, a1 = 0.0f;
        #pragma unroll 16
        for (int k = 0; k < RR; ++k) {
            float w = AT[k * RR + c];
            a0 = fmaf(x0[k], w, a0);
            a1 = fmaf(x1[k], w, a1);
        }
        const float* i0 = inputs + (r0 * TT + (t + 1)) * DD;
        const float* i1 = i0 + TT * DD;
        const float* m0 = mc + r0 * DD;
        const float* m1 = m0 + DD;
        float b0 = 0.0f, b1 = 0.0f;
        #pragma unroll 16
        for (int d = 0; d < DD; ++d) {
            float w  = BT[d * RR + c];
            float u0 = i0[d] + m0[d];
            float u1 = i1[d] + m1[d];
            b0 = fmaf(u0, w, b0);
            b1 = fmaf(u1, w, b1);
        }
        xn[r0 * RR + c]       = a0 + b0;
        xn[(r0 + 1) * RR + c] = a1 + b1;
        // __syncthreads drains vmcnt(0) (all tile stores in L2); release
        // fetch_add writes back L2 (agent scope) and bumps the counter.
        __syncthreads();
        if (tid == 0)
            __hip_atomic_fetch_add(&cnt[rg], 1u, __ATOMIC_RELEASE,
                                   __HIP_MEMORY_SCOPE_AGENT);
    } else {
        // ================= m-part (overlapped consumer) =================
        if (t >= TT - 1) return;
        const int g  = bid - 256;          // 0..63
        const int r0 = g * 2;              // 2 rows
        const int rg = r0 >> 3;            // x-tile row-group
        const unsigned int tgt = 8u * (unsigned int)(t + 2);
        if (tid == 0) {
            while (__hip_atomic_load(&cnt[rg], __ATOMIC_ACQUIRE,
                                     __HIP_MEMORY_SCOPE_AGENT) < tgt)
                __builtin_amdgcn_s_sleep(1);
        }
        __syncthreads();
        const int c = tid;                 // 0..255
        const float* xr0 = xn + r0 * RR;
        const float* xr1 = xr0 + RR;
        float a0 = 0.0f, a1 = 0.0f;
        #pragma unroll 16
        for (int k = 0; k < RR; ++k) {
            float w = CT[k * DD + c];
            a0 = fmaf(xr0[k], w, a0);
            a1 = fmaf(xr1[k], w, a1);
        }
        mn[r0 * DD + c]       = a0;
        mn[(r0 + 1) * DD + c] = a1;
    }
}

__global__ __launch_bounds__(64) void sentinel_kernel(float* __restrict__ out, float v)
{
    if (threadIdx.x == 0 && blockIdx.x == 0) out[0] = v;
}

extern "C" void kernel_launch(void* const* d_in, const int* in_sizes, int n_in,
                              void* d_out, int out_size, void* d_ws, size_t ws_size,
                              hipStream_t stream)
{
    const float* inputs = (const float*)d_in[0];
    const float* wfm    = (const float*)d_in[1];
    const float* WyhT   = (const float*)d_in[2];
    const float* WyxT   = (const float*)d_in[3];
    const float* WyfT   = (const float*)d_in[4];
    const float* by     = (const float*)d_in[5];
    const float* AT     = (const float*)d_in[6];
    const float* BT     = (const float*)d_in[7];
    const float* CT     = (const float*)d_in[8];
    float* out = (float*)d_out;
    float* ws  = (float*)d_ws;

    // Environment sentinels (absmax reveals code if triggered).
    double code = 0.0;
    static const int exp_sizes[9] = {8388608, 256, 262144, 262144, 131072,
                                     512, 262144, 131072, 131072};
    if (n_in != 9) {
        code = 3.0e6 + n_in;
    } else {
        for (int i = 0; i < 9; ++i)
            if (in_sizes[i] != exp_sizes[i]) { code = 2.0e6 + i * 1.0e4; break; }
    }
    if (code == 0.0 && out_size != BB * TT * UU)
        code = 4.0e6 + (double)(out_size / 10000);
    if (code == 0.0 && ws_size < (size_t)WS_NEED_BYTES)
        code = 1.0e6 + (double)(ws_size / 1024);
    if (code != 0.0) {
        sentinel_kernel<<<1, 64, 0, stream>>>(out, (float)code);
        return;
    }

    float* X0 = ws + OFF_X0;
    float* X1 = ws + OFF_X1;
    float* M0 = ws + OFF_M0;
    float* M1 = ws + OFF_M1;
    float* HZ = ws + OFF_HZ;
    unsigned int* CN = reinterpret_cast<unsigned int*>(ws + OFF_CN);

    // Zero x_{-1} (X1), m_{-1} (M1), h_{-1} (HZ), counters. (Whole region for safety.)
    zero_kernel<<<(WS_FLT + 255) / 256, 256, 0, stream>>>(ws, WS_FLT);

    // t = -1..255: one launch per step.
    //   t=-1: x->x_0 (X0), m->m_0 (M0); h skipped (reads of X1/M1 zeros).
    //   t=0..254: h_t ; x_{t+1} ; m_{t+1}.
    //   t=255: h_255 only.
    for (int t = -1; t < TT; ++t) {
        const float* xc = (t & 1) ? X1 : X0;          // x_t
        float*       xnp = (t & 1) ? X0 : X1;         // x_{t+1}
        const float* mcp = (t & 1) ? M1 : M0;         // m_t
        float*       mnp = (t & 1) ? M0 : M1;         // m_{t+1}
        combo_kernel<<<320, 256, 0, stream>>>(inputs, wfm, by, WyhT, WyxT, WyfT,
                                              AT, BT, CT, xc, mcp, HZ, xnp, mnp,
                                              CN, out, t);
    }
}